// Round 4
// baseline (136.931 us; speedup 1.0000x reference)
//
#include <hip/hip_runtime.h>

// Problem constants
#define BB 64
#define NN 512
#define MM 30
#define E2 4
#define NE 32
#define NE4 8
#define NF 64
#define BN_TOTAL (BB * NN)   // 32768
#define GP 31                 // padded row length for transposed G (conflict-free)

__device__ __forceinline__ float fsig(float x)  { return 1.0f / (1.0f + __expf(-x)); }
__device__ __forceinline__ float ftanh(float x) { return 1.0f - 2.0f / (1.0f + __expf(2.0f * x)); }

// ---------------------------------------------------------------------------
// K1 v2: per-point embedding MLP + bilinear contraction -> D[bn][256]
// 1 wave per block; block handles 2 (b,n) pairs; lane = m-point.
// Changes vs v1:
//  - G stored TRANSPOSED in LDS: G_lds[half][j][m], row pad 31.
//      write: lane n stores g[j] at j*31+n  -> lane-consecutive, conflict-free
//      Bm read: lane n reads row n          -> bank (m-n)%32, conflict-free
//      A  read: 8 rows, 4-lane broadcast    -> conflict-free
//  - __launch_bounds__(64,1): regalloc free to use up to 512 VGPRs (occupancy
//    is LDS-capped at ~15 blocks/CU regardless) -> no spill/remat traffic.
//  - layers 1/2 computed in two 16-feature chunks (same per-output summation
//    order -> bit-identical) so peak liveness ~48 floats.
// ---------------------------------------------------------------------------
__global__ __launch_bounds__(64, 1) void k_emb(
    const float* __restrict__ Sg, const float* __restrict__ R,
    const float* __restrict__ We0, const float* __restrict__ be0,
    const float* __restrict__ We1, const float* __restrict__ be1,
    const float* __restrict__ We2, const float* __restrict__ be2,
    float* __restrict__ Dout)
{
    __shared__ float G_lds[2][NE][GP];     // 7936 B, transposed [feature][m]
    __shared__ float R_lds[2][MM][4];      //  960 B
    __shared__ float A_lds[2][NE4][4];     //  256 B
    __shared__ float Bm_lds[2][4][NE];     // 1024 B

    const int l    = threadIdx.x;
    const int half = l >> 5;
    const int n    = l & 31;
    const int bn   = blockIdx.x * 2 + half;
    const bool act = (n < MM);
    const int m_eff = act ? n : (MM - 1);   // clamp to stay in-bounds

    const float4 s4 = ((const float4*)Sg)[(size_t)bn * MM + m_eff];
    const float4 r4 = ((const float4*)R )[(size_t)bn * MM + m_eff];
    const float sg[4] = { s4.x, s4.y, s4.z, s4.w };

    // ---- layer 0: 4 -> 32, sigmoid ----
    float h0[NE];
#pragma unroll
    for (int j = 0; j < NE; ++j) {
        float a = be0[j];
#pragma unroll
        for (int i = 0; i < E2; ++i) a += sg[i] * We0[i * NE + j];
        h0[j] = fsig(a);
    }

    // ---- layer 1: 32 -> 32, tanh; two 16-feature chunks (same j-order) ----
    float h1[NE];
#pragma unroll
    for (int c = 0; c < 2; ++c) {
        const int jb = c * 16;
#pragma unroll
        for (int j = 0; j < 16; ++j) h1[jb + j] = be1[jb + j];
#pragma unroll
        for (int i = 0; i < NE; ++i) {
            const float hi = h0[i];
#pragma unroll
            for (int j = 0; j < 16; ++j) h1[jb + j] += hi * We1[i * NE + jb + j];
        }
    }
#pragma unroll
    for (int j = 0; j < NE; ++j) h1[j] = ftanh(h1[j]);

    // ---- layer 2: 32 -> 32; two 16-feature chunks; store transposed ----
#pragma unroll
    for (int c = 0; c < 2; ++c) {
        const int jb = c * 16;
        float g[16];
#pragma unroll
        for (int j = 0; j < 16; ++j) g[j] = be2[jb + j];
#pragma unroll
        for (int i = 0; i < NE; ++i) {
            const float hi = h1[i];
#pragma unroll
            for (int j = 0; j < 16; ++j) g[j] += hi * We2[i * NE + jb + j];
        }
        if (act) {
#pragma unroll
            for (int j = 0; j < 16; ++j) G_lds[half][jb + j][n] = g[j];
        }
    }
    if (act) *(float4*)&R_lds[half][n][0] = r4;
    __syncthreads();

    // ---- Bm[l][n] = sum_m R[m][l] * G[m][n]  (lane n = feature) ----
    float bm[4] = {0.f, 0.f, 0.f, 0.f};
    const float* __restrict__ grow = &G_lds[half][n][0];
#pragma unroll 5
    for (int mm = 0; mm < MM; ++mm) {
        const float gv = grow[mm];
        const float4 rr = *(const float4*)&R_lds[half][mm][0];
        bm[0] += rr.x * gv;
        bm[1] += rr.y * gv;
        bm[2] += rr.z * gv;
        bm[3] += rr.w * gv;
    }
#pragma unroll
    for (int li = 0; li < 4; ++li) Bm_lds[half][li][n] = bm[li];

    // ---- A[k][li] = sum_m G[m][k] * R[m][li] ----
    {
        const int k  = n & 7;
        const int li = n >> 3;
        const float* __restrict__ gk = &G_lds[half][k][0];
        float a = 0.f;
#pragma unroll 5
        for (int mm = 0; mm < MM; ++mm)
            a += gk[mm] * R_lds[half][mm][li];
        A_lds[half][k][li] = a;
    }
    __syncthreads();

    // ---- D[k][n] = sum_l A[k][l] * Bm[l][n]; write coalesced ----
    const float4 b0 = make_float4(Bm_lds[half][0][n], Bm_lds[half][1][n],
                                  Bm_lds[half][2][n], Bm_lds[half][3][n]);
#pragma unroll
    for (int k = 0; k < NE4; ++k) {
        const float4 ak = *(const float4*)&A_lds[half][k][0];
        const float d = ak.x * b0.x + ak.y * b0.y + ak.z * b0.z + ak.w * b0.w;
        Dout[(size_t)bn * 256 + k * NE + n] = d;
    }
}

// ---------------------------------------------------------------------------
// K2 v3: fit MLP, feature-split waves + provably-uniform weight addressing.
// ---------------------------------------------------------------------------
__global__ __launch_bounds__(256) void k_fit2(
    const float* __restrict__ D,
    const float* __restrict__ Wf0, const float* __restrict__ bf0,
    const float* __restrict__ Wf1, const float* __restrict__ bf1,
    const float* __restrict__ Wf2, const float* __restrict__ bf2,
    const float* __restrict__ Wf3, const float* __restrict__ bf3,
    float* __restrict__ Q)
{
    __shared__ float HT0[64 * 64];   // 16 KB, [f][row]
    __shared__ float HT1[64 * 64];   // 16 KB, [f][row]

    const int tid = threadIdx.x;
    const int r   = tid & 63;          // lane: row within block
    const int row = blockIdx.x * 64 + r;
    const int f0  = __builtin_amdgcn_readfirstlane(tid >> 6) * 16;

    // ---- layer 0: 256 -> 64 (this wave: 16 features), k order preserved ----
    float h[16];
#pragma unroll
    for (int j = 0; j < 16; ++j) h[j] = bf0[f0 + j];

    const float4* __restrict__ d4 = (const float4*)(D + (size_t)row * 256);
#pragma unroll 8
    for (int kk = 0; kk < 64; ++kk) {
        const float4 dv = d4[kk];
#pragma unroll
        for (int e = 0; e < 4; ++e) {
            const float dval = (&dv.x)[e];
            const float* __restrict__ w = Wf0 + (size_t)(kk * 4 + e) * NF + f0;
#pragma unroll
            for (int j = 0; j < 16; ++j) h[j] += dval * w[j];
        }
    }
#pragma unroll
    for (int j = 0; j < 16; ++j) HT0[(f0 + j) * 64 + r] = ftanh(h[j]);
    __syncthreads();

    // ---- layer 1: 64 -> 64, sigmoid ----
    float h2[16];
#pragma unroll
    for (int j = 0; j < 16; ++j) h2[j] = bf1[f0 + j];
#pragma unroll 8
    for (int k = 0; k < 64; ++k) {
        const float hv = HT0[k * 64 + r];
        const float* __restrict__ w = Wf1 + (size_t)k * NF + f0;
#pragma unroll
        for (int j = 0; j < 16; ++j) h2[j] += hv * w[j];
    }
#pragma unroll
    for (int j = 0; j < 16; ++j) HT1[(f0 + j) * 64 + r] = fsig(h2[j]);
    __syncthreads();

    // ---- layer 2: 64 -> 64, tanh (results stay in registers) ----
#pragma unroll
    for (int j = 0; j < 16; ++j) h[j] = bf2[f0 + j];
#pragma unroll 8
    for (int k = 0; k < 64; ++k) {
        const float hv = HT1[k * 64 + r];
        const float* __restrict__ w = Wf2 + (size_t)k * NF + f0;
#pragma unroll
        for (int j = 0; j < 16; ++j) h[j] += hv * w[j];
    }

    // ---- layer 3 partial: this wave's 16 features ----
    float qp = 0.f;
#pragma unroll
    for (int j = 0; j < 16; ++j) qp += ftanh(h[j]) * Wf3[f0 + j];

    float* Qp = HT0;   // HT0 dead; reuse
    Qp[(tid >> 6) * 64 + r] = qp;
    __syncthreads();

    if (tid < 64) {
        const float q = bf3[0] + Qp[tid] + Qp[64 + tid] + Qp[128 + tid] + Qp[192 + tid];
        Q[(size_t)blockIdx.x * 64 + tid] = q;
    }
}

// ---------------------------------------------------------------------------
// K3: deterministic mean over N per batch element.
// ---------------------------------------------------------------------------
__global__ __launch_bounds__(256) void k_mean(const float* __restrict__ Q,
                                              float* __restrict__ out)
{
    __shared__ float s[256];
    const int b = blockIdx.x;
    const int t = threadIdx.x;
    float v = Q[b * NN + t] + Q[b * NN + 256 + t];
    s[t] = v;
    __syncthreads();
#pragma unroll
    for (int off = 128; off > 0; off >>= 1) {
        if (t < off) s[t] += s[t + off];
        __syncthreads();
    }
    if (t == 0) out[b] = s[0] * (1.0f / (float)NN);
}

// ---------------------------------------------------------------------------
extern "C" void kernel_launch(void* const* d_in, const int* in_sizes, int n_in,
                              void* d_out, int out_size, void* d_ws, size_t ws_size,
                              hipStream_t stream)
{
    const float* Sg  = (const float*)d_in[0];
    const float* R   = (const float*)d_in[1];
    const float* We0 = (const float*)d_in[2];
    const float* be0 = (const float*)d_in[3];
    const float* We1 = (const float*)d_in[4];
    const float* be1 = (const float*)d_in[5];
    const float* We2 = (const float*)d_in[6];
    const float* be2 = (const float*)d_in[7];
    const float* Wf0 = (const float*)d_in[8];
    const float* bf0 = (const float*)d_in[9];
    const float* Wf1 = (const float*)d_in[10];
    const float* bf1 = (const float*)d_in[11];
    const float* Wf2 = (const float*)d_in[12];
    const float* bf2 = (const float*)d_in[13];
    const float* Wf3 = (const float*)d_in[14];
    const float* bf3 = (const float*)d_in[15];

    float* D = (float*)d_ws;                                  // 33.55 MB
    float* Q = (float*)((char*)d_ws + (size_t)BN_TOTAL * 256 * sizeof(float)); // 128 KB

    k_emb<<<BN_TOTAL / 2, 64, 0, stream>>>(Sg, R, We0, be0, We1, be1, We2, be2, D);
    k_fit2<<<BN_TOTAL / 64, 256, 0, stream>>>(D, Wf0, bf0, Wf1, bf1, Wf2, bf2, Wf3, bf3, Q);
    k_mean<<<BB, 256, 0, stream>>>(Q, (float*)d_out);
}

// Round 5
// 99.577 us; speedup vs baseline: 1.3751x; 1.3751x over previous
//
#include <hip/hip_runtime.h>

// Problem constants
#define BB 64
#define NN 512
#define MM 30
#define E2 4
#define NE 32
#define NE4 8
#define NF 64
#define BN_TOTAL (BB * NN)   // 32768
#define TP 36                 // padded row (floats) of the h1 transpose tile

typedef __attribute__((ext_vector_type(8))) short bf16x8;
typedef __attribute__((ext_vector_type(4))) float vf4;

__device__ __forceinline__ float fsig(float x)  { return 1.0f / (1.0f + __expf(-x)); }
__device__ __forceinline__ float ftanh(float x) { return 1.0f - 2.0f / (1.0f + __expf(2.0f * x)); }

union fragu { unsigned u[4]; bf16x8 v; };

__device__ __forceinline__ unsigned cvt_pk_bf16(float a, float b) {
    unsigned r;
    asm("v_cvt_pk_bf16_f32 %0, %1, %2" : "=v"(r) : "v"(a), "v"(b));
    return r;
}
__device__ __forceinline__ float lo16f(unsigned u) { return __uint_as_float(u << 16); }
__device__ __forceinline__ float hi16f(unsigned u) { return __uint_as_float(u & 0xFFFF0000u); }

// Split 8 fp32 (a.xyzw, b.xyzw) into hi/lo bf16 fragments (RNE via v_cvt_pk_bf16_f32).
__device__ __forceinline__ void split8v(vf4 a, vf4 b, bf16x8& hi, bf16x8& lo) {
    fragu H, L;
    H.u[0] = cvt_pk_bf16(a.x, a.y);
    H.u[1] = cvt_pk_bf16(a.z, a.w);
    H.u[2] = cvt_pk_bf16(b.x, b.y);
    H.u[3] = cvt_pk_bf16(b.z, b.w);
    L.u[0] = cvt_pk_bf16(a.x - lo16f(H.u[0]), a.y - hi16f(H.u[0]));
    L.u[1] = cvt_pk_bf16(a.z - lo16f(H.u[1]), a.w - hi16f(H.u[1]));
    L.u[2] = cvt_pk_bf16(b.x - lo16f(H.u[2]), b.y - hi16f(H.u[2]));
    L.u[3] = cvt_pk_bf16(b.x == b.x ? b.z - lo16f(H.u[3]) : 0.f, b.w - hi16f(H.u[3]));
    hi = H.v; lo = L.v;
}

// 3-term split-precision MFMA: C += A*B with A=Ah+Al, B=Bh+Bl (lolo dropped).
__device__ __forceinline__ vf4 mm3(bf16x8 ah, bf16x8 al, bf16x8 bh, bf16x8 bl, vf4 c) {
    c = __builtin_amdgcn_mfma_f32_16x16x32_bf16(ah, bh, c, 0, 0, 0);
    c = __builtin_amdgcn_mfma_f32_16x16x32_bf16(ah, bl, c, 0, 0, 0);
    c = __builtin_amdgcn_mfma_f32_16x16x32_bf16(al, bh, c, 0, 0, 0);
    return c;
}

__device__ __forceinline__ vf4 ld4(const float* p) { return *(const vf4*)p; }

// ---------------------------------------------------------------------------
// K1 v3 (MFMA): one wave per (b,n) pair. Lane l: row0=l&15 (point-in-tile /
// B-col), grp=l>>4 (k-group). Layers 1,2 are [32x32]@[32x32] bf16-split MFMA
// (2 M-tiles x 2 N-tiles x 3 split = 12 MFMA/layer). Identity A[k][l]=Bm[l][k]
// => D = Bm^T Bm, computed from G fragments + LDS-broadcast R. Pad points
// 30,31 are neutralized by zeroed R rows. No __syncthreads (same-wave LDS).
// ---------------------------------------------------------------------------
__global__ __launch_bounds__(256, 1) void k_emb_mfma(
    const float* __restrict__ Sg, const float* __restrict__ R,
    const float* __restrict__ We0, const float* __restrict__ be0,
    const float* __restrict__ We1, const float* __restrict__ be1,
    const float* __restrict__ We2, const float* __restrict__ be2,
    float* __restrict__ Dout)
{
    __shared__ float T[4][32 * TP];    // h1 transpose tile, per wave, 4608 B
    __shared__ vf4   Rl[4][32];        // R rows (30,31 zeroed), per wave

    const int tid  = threadIdx.x;
    const int w    = tid >> 6;
    const int l    = tid & 63;
    const int row0 = l & 15;
    const int grp  = l >> 4;
    const int pair = blockIdx.x * 4 + w;

    // ---- stage R (rows 30,31 = 0) ----
    if (l < 32) {
        vf4 rv = 0.f;
        if (l < MM) rv = ld4(R + ((size_t)pair * MM + l) * 4);
        Rl[w][l] = rv;
    }

    // ---- layer 0: 4 -> 32, sigmoid; build A-frags for layer 1 ----
    // lane computes h0[point = 16t+row0][feature = grp*8+e], e=0..7
    vf4 w0[4][2];
#pragma unroll
    for (int i = 0; i < 4; ++i) {
        w0[i][0] = ld4(We0 + i * NE + grp * 8);
        w0[i][1] = ld4(We0 + i * NE + grp * 8 + 4);
    }
    const vf4 b0a = ld4(be0 + grp * 8);
    const vf4 b0b = ld4(be0 + grp * 8 + 4);

    bf16x8 Ah[2], Al[2];
#pragma unroll
    for (int t = 0; t < 2; ++t) {
        const int p = 16 * t + row0;
        vf4 s = 0.f;
        if (p < MM) s = ld4(Sg + ((size_t)pair * MM + p) * 4);
        vf4 acc0 = b0a + s.x * w0[0][0] + s.y * w0[1][0] + s.z * w0[2][0] + s.w * w0[3][0];
        vf4 acc1 = b0b + s.x * w0[0][1] + s.y * w0[1][1] + s.z * w0[2][1] + s.w * w0[3][1];
#pragma unroll
        for (int e = 0; e < 4; ++e) { acc0[e] = fsig(acc0[e]); acc1[e] = fsig(acc1[e]); }
        split8v(acc0, acc1, Ah[t], Al[t]);
    }

    // ---- B-fragments for layer 1: We1[k][col], k=grp*8+e, col=row0+16nt ----
    bf16x8 B1h[2], B1l[2];
#pragma unroll
    for (int nt = 0; nt < 2; ++nt) {
        const float* wp = We1 + (size_t)(grp * 8) * NE + nt * 16 + row0;
        vf4 x0 = { wp[0],       wp[NE],     wp[2 * NE], wp[3 * NE] };
        vf4 x1 = { wp[4 * NE],  wp[5 * NE], wp[6 * NE], wp[7 * NE] };
        split8v(x0, x1, B1h[nt], B1l[nt]);
    }

    // ---- layer 1 MFMA: h1 = h0 @ We1 + be1, tanh ----
    const float bias1[2] = { be1[row0], be1[row0 + 16] };
    vf4 H1[2][2];
#pragma unroll
    for (int t = 0; t < 2; ++t)
#pragma unroll
        for (int nt = 0; nt < 2; ++nt) {
            vf4 z = 0.f;
            H1[t][nt] = mm3(Ah[t], Al[t], B1h[nt], B1l[nt], z);
        }

    // write tanh(h1) transposed tile: T[point][feature]
#pragma unroll
    for (int t = 0; t < 2; ++t)
#pragma unroll
        for (int nt = 0; nt < 2; ++nt)
#pragma unroll
            for (int e = 0; e < 4; ++e) {
                const float v = ftanh(H1[t][nt][e] + bias1[nt]);
                T[w][(grp * 4 + e + 16 * t) * TP + row0 + 16 * nt] = v;
            }

    // read back as layer-2 A-frags: lane needs T[16t+row0][grp*8 .. +8]
    bf16x8 A2h[2], A2l[2];
#pragma unroll
    for (int t = 0; t < 2; ++t) {
        const float* src = &T[w][(16 * t + row0) * TP + grp * 8];
        vf4 x0 = *(const vf4*)(src);
        vf4 x1 = *(const vf4*)(src + 4);
        split8v(x0, x1, A2h[t], A2l[t]);
    }

    // ---- B-fragments for layer 2 ----
    bf16x8 B2h[2], B2l[2];
#pragma unroll
    for (int nt = 0; nt < 2; ++nt) {
        const float* wp = We2 + (size_t)(grp * 8) * NE + nt * 16 + row0;
        vf4 x0 = { wp[0],       wp[NE],     wp[2 * NE], wp[3 * NE] };
        vf4 x1 = { wp[4 * NE],  wp[5 * NE], wp[6 * NE], wp[7 * NE] };
        split8v(x0, x1, B2h[nt], B2l[nt]);
    }

    // ---- layer 2 MFMA: G = h1' @ We2 + be2 (no activation) ----
    const float bias2[2] = { be2[row0], be2[row0 + 16] };
    vf4 G[2][2];
#pragma unroll
    for (int t = 0; t < 2; ++t)
#pragma unroll
        for (int nt = 0; nt < 2; ++nt) {
            vf4 z = 0.f;
            G[t][nt] = mm3(A2h[t], A2l[t], B2h[nt], B2l[nt], z);
#pragma unroll
            for (int e = 0; e < 4; ++e) G[t][nt][e] += bias2[nt];
        }

    // ---- Bm[l][col] = sum_m R[m][l] * G[m][col]  (per-lane partial over its
    //      8 rows, then xor16/xor32 combine; pad rows have R=0) ----
    float bm[4][2] = {{0.f, 0.f}, {0.f, 0.f}, {0.f, 0.f}, {0.f, 0.f}};
#pragma unroll
    for (int t = 0; t < 2; ++t)
#pragma unroll
        for (int e = 0; e < 4; ++e) {
            const int rrow = grp * 4 + e + 16 * t;
            const vf4 r4 = Rl[w][rrow];
#pragma unroll
            for (int nt = 0; nt < 2; ++nt) {
                const float gv = G[t][nt][e];
                bm[0][nt] += r4.x * gv;
                bm[1][nt] += r4.y * gv;
                bm[2][nt] += r4.z * gv;
                bm[3][nt] += r4.w * gv;
            }
        }
    float bmv[4][2];
#pragma unroll
    for (int li = 0; li < 4; ++li)
#pragma unroll
        for (int nt = 0; nt < 2; ++nt) {
            float v = bm[li][nt];
            v += __shfl_xor(v, 16);
            v += __shfl_xor(v, 32);
            bmv[li][nt] = v;
        }

    // ---- D[k][n] = sum_l Bm[l][k] * Bm[l][n], k<8; this lane: k=2grp+kk,
    //      n = row0 + 16nt. Bm[l][k] broadcast from lane k (col k, nt=0). ----
    float d[2][2] = {{0.f, 0.f}, {0.f, 0.f}};
#pragma unroll
    for (int kk = 0; kk < 2; ++kk) {
        const int src = grp * 2 + kk;
#pragma unroll
        for (int li = 0; li < 4; ++li) {
            const float a = __shfl(bmv[li][0], src);
#pragma unroll
            for (int nt = 0; nt < 2; ++nt) d[kk][nt] += a * bmv[li][nt];
        }
    }

    float* dp = Dout + (size_t)pair * 256;
#pragma unroll
    for (int kk = 0; kk < 2; ++kk)
#pragma unroll
        for (int nt = 0; nt < 2; ++nt)
            dp[(grp * 2 + kk) * NE + nt * 16 + row0] = d[kk][nt];
}

// ---------------------------------------------------------------------------
// K2 v3: fit MLP, feature-split waves + provably-uniform weight addressing.
// ---------------------------------------------------------------------------
__global__ __launch_bounds__(256) void k_fit2(
    const float* __restrict__ D,
    const float* __restrict__ Wf0, const float* __restrict__ bf0,
    const float* __restrict__ Wf1, const float* __restrict__ bf1,
    const float* __restrict__ Wf2, const float* __restrict__ bf2,
    const float* __restrict__ Wf3, const float* __restrict__ bf3,
    float* __restrict__ Q)
{
    __shared__ float HT0[64 * 64];   // 16 KB, [f][row]
    __shared__ float HT1[64 * 64];   // 16 KB, [f][row]

    const int tid = threadIdx.x;
    const int r   = tid & 63;          // lane: row within block
    const int row = blockIdx.x * 64 + r;
    const int f0  = __builtin_amdgcn_readfirstlane(tid >> 6) * 16;

    // ---- layer 0: 256 -> 64 (this wave: 16 features), k order preserved ----
    float h[16];
#pragma unroll
    for (int j = 0; j < 16; ++j) h[j] = bf0[f0 + j];

    const float4* __restrict__ d4 = (const float4*)(D + (size_t)row * 256);
#pragma unroll 8
    for (int kk = 0; kk < 64; ++kk) {
        const float4 dv = d4[kk];
#pragma unroll
        for (int e = 0; e < 4; ++e) {
            const float dval = (&dv.x)[e];
            const float* __restrict__ wv = Wf0 + (size_t)(kk * 4 + e) * NF + f0;
#pragma unroll
            for (int j = 0; j < 16; ++j) h[j] += dval * wv[j];
        }
    }
#pragma unroll
    for (int j = 0; j < 16; ++j) HT0[(f0 + j) * 64 + r] = ftanh(h[j]);
    __syncthreads();

    // ---- layer 1: 64 -> 64, sigmoid ----
    float h2[16];
#pragma unroll
    for (int j = 0; j < 16; ++j) h2[j] = bf1[f0 + j];
#pragma unroll 8
    for (int k = 0; k < 64; ++k) {
        const float hv = HT0[k * 64 + r];
        const float* __restrict__ wv = Wf1 + (size_t)k * NF + f0;
#pragma unroll
        for (int j = 0; j < 16; ++j) h2[j] += hv * wv[j];
    }
#pragma unroll
    for (int j = 0; j < 16; ++j) HT1[(f0 + j) * 64 + r] = fsig(h2[j]);
    __syncthreads();

    // ---- layer 2: 64 -> 64, tanh (results stay in registers) ----
#pragma unroll
    for (int j = 0; j < 16; ++j) h[j] = bf2[f0 + j];
#pragma unroll 8
    for (int k = 0; k < 64; ++k) {
        const float hv = HT1[k * 64 + r];
        const float* __restrict__ wv = Wf2 + (size_t)k * NF + f0;
#pragma unroll
        for (int j = 0; j < 16; ++j) h[j] += hv * wv[j];
    }

    // ---- layer 3 partial: this wave's 16 features ----
    float qp = 0.f;
#pragma unroll
    for (int j = 0; j < 16; ++j) qp += ftanh(h[j]) * Wf3[f0 + j];

    float* Qp = HT0;   // HT0 dead; reuse
    Qp[(tid >> 6) * 64 + r] = qp;
    __syncthreads();

    if (tid < 64) {
        const float q = bf3[0] + Qp[tid] + Qp[64 + tid] + Qp[128 + tid] + Qp[192 + tid];
        Q[(size_t)blockIdx.x * 64 + tid] = q;
    }
}

// ---------------------------------------------------------------------------
// K3: deterministic mean over N per batch element.
// ---------------------------------------------------------------------------
__global__ __launch_bounds__(256) void k_mean(const float* __restrict__ Q,
                                              float* __restrict__ out)
{
    __shared__ float s[256];
    const int b = blockIdx.x;
    const int t = threadIdx.x;
    float v = Q[b * NN + t] + Q[b * NN + 256 + t];
    s[t] = v;
    __syncthreads();
#pragma unroll
    for (int off = 128; off > 0; off >>= 1) {
        if (t < off) s[t] += s[t + off];
        __syncthreads();
    }
    if (t == 0) out[b] = s[0] * (1.0f / (float)NN);
}

// ---------------------------------------------------------------------------
extern "C" void kernel_launch(void* const* d_in, const int* in_sizes, int n_in,
                              void* d_out, int out_size, void* d_ws, size_t ws_size,
                              hipStream_t stream)
{
    const float* Sg  = (const float*)d_in[0];
    const float* R   = (const float*)d_in[1];
    const float* We0 = (const float*)d_in[2];
    const float* be0 = (const float*)d_in[3];
    const float* We1 = (const float*)d_in[4];
    const float* be1 = (const float*)d_in[5];
    const float* We2 = (const float*)d_in[6];
    const float* be2 = (const float*)d_in[7];
    const float* Wf0 = (const float*)d_in[8];
    const float* bf0 = (const float*)d_in[9];
    const float* Wf1 = (const float*)d_in[10];
    const float* bf1 = (const float*)d_in[11];
    const float* Wf2 = (const float*)d_in[12];
    const float* bf2 = (const float*)d_in[13];
    const float* Wf3 = (const float*)d_in[14];
    const float* bf3 = (const float*)d_in[15];

    float* D = (float*)d_ws;                                  // 33.55 MB
    float* Q = (float*)((char*)d_ws + (size_t)BN_TOTAL * 256 * sizeof(float)); // 128 KB

    k_emb_mfma<<<BN_TOTAL / 4, 256, 0, stream>>>(Sg, R, We0, be0, We1, be1, We2, be2, D);
    k_fit2<<<BN_TOTAL / 64, 256, 0, stream>>>(D, Wf0, bf0, Wf1, bf1, Wf2, bf2, Wf3, bf3, Q);
    k_mean<<<BB, 256, 0, stream>>>(Q, (float*)d_out);
}

// Round 6
// 97.300 us; speedup vs baseline: 1.4073x; 1.0234x over previous
//
#include <hip/hip_runtime.h>

// Problem constants
#define BB 64
#define NN 512
#define MM 30
#define E2 4
#define NE 32
#define NE4 8
#define NF 64
#define BN_TOTAL (BB * NN)   // 32768
#define TP 36                 // padded row (floats) of the h1 transpose tile
#define NPAIR 4               // pairs processed per wave (amortizes weight setup)

typedef __attribute__((ext_vector_type(8))) short bf16x8;
typedef __attribute__((ext_vector_type(4))) float vf4;

__device__ __forceinline__ float fsig(float x)  { return 1.0f / (1.0f + __expf(-x)); }
__device__ __forceinline__ float ftanh(float x) { return 1.0f - 2.0f / (1.0f + __expf(2.0f * x)); }

union fragu { unsigned u[4]; bf16x8 v; };

__device__ __forceinline__ unsigned cvt_pk_bf16(float a, float b) {
    unsigned r;
    asm("v_cvt_pk_bf16_f32 %0, %1, %2" : "=v"(r) : "v"(a), "v"(b));
    return r;
}
__device__ __forceinline__ float lo16f(unsigned u) { return __uint_as_float(u << 16); }
__device__ __forceinline__ float hi16f(unsigned u) { return __uint_as_float(u & 0xFFFF0000u); }

// Split 8 fp32 (a.xyzw, b.xyzw) into hi/lo bf16 fragments (RNE via v_cvt_pk_bf16_f32).
__device__ __forceinline__ void split8v(vf4 a, vf4 b, bf16x8& hi, bf16x8& lo) {
    fragu H, L;
    H.u[0] = cvt_pk_bf16(a.x, a.y);
    H.u[1] = cvt_pk_bf16(a.z, a.w);
    H.u[2] = cvt_pk_bf16(b.x, b.y);
    H.u[3] = cvt_pk_bf16(b.z, b.w);
    L.u[0] = cvt_pk_bf16(a.x - lo16f(H.u[0]), a.y - hi16f(H.u[0]));
    L.u[1] = cvt_pk_bf16(a.z - lo16f(H.u[1]), a.w - hi16f(H.u[1]));
    L.u[2] = cvt_pk_bf16(b.x - lo16f(H.u[2]), b.y - hi16f(H.u[2]));
    L.u[3] = cvt_pk_bf16(b.z - lo16f(H.u[3]), b.w - hi16f(H.u[3]));
    hi = H.v; lo = L.v;
}

// 3-term split-precision MFMA: C += A*B with A=Ah+Al, B=Bh+Bl (lolo dropped).
__device__ __forceinline__ vf4 mm3(bf16x8 ah, bf16x8 al, bf16x8 bh, bf16x8 bl, vf4 c) {
    c = __builtin_amdgcn_mfma_f32_16x16x32_bf16(ah, bh, c, 0, 0, 0);
    c = __builtin_amdgcn_mfma_f32_16x16x32_bf16(ah, bl, c, 0, 0, 0);
    c = __builtin_amdgcn_mfma_f32_16x16x32_bf16(al, bh, c, 0, 0, 0);
    return c;
}

__device__ __forceinline__ vf4 ld4(const float* p) { return *(const vf4*)p; }

// ---------------------------------------------------------------------------
// K1 v4 (MFMA, batched): one wave per NPAIR=4 (b,n) pairs.
// Weight fragments (w0, B1, B2, biases) built ONCE per wave and kept in
// registers across the pair loop; biases folded into the MFMA accumulator
// init (C col=lane&15 => bias per-lane constant across regs).
// Verified layouts from v3 (absmax 0.0): A row=lane&15, k=(lane>>4)*8+e;
// B k=(lane>>4)*8+e, col=lane&15; C col=lane&15, row=(lane>>4)*4+reg.
// Identity A[k][l]=Bm[l][k] => D = Bm^T Bm. Pad rows 30,31 have R=0.
// No __syncthreads: all LDS traffic is same-wave (T is per-wave private).
// ---------------------------------------------------------------------------
__global__ __launch_bounds__(256) void k_emb_mfma(
    const float* __restrict__ Sg, const float* __restrict__ R,
    const float* __restrict__ We0, const float* __restrict__ be0,
    const float* __restrict__ We1, const float* __restrict__ be1,
    const float* __restrict__ We2, const float* __restrict__ be2,
    float* __restrict__ Dout)
{
    __shared__ float T[4][32 * TP];        // h1 transpose tile, per wave, 4608 B
    __shared__ vf4   Rl[4][NPAIR][32];     // R rows (30,31 zeroed), 2 KB/wave

    const int tid   = threadIdx.x;
    const int w     = tid >> 6;
    const int l     = tid & 63;
    const int row0  = l & 15;
    const int grp   = l >> 4;
    const int pair0 = (blockIdx.x * 4 + w) * NPAIR;

    // ---- stage R for all 4 pairs (2 coalesced rounds of 64 rows) ----
#pragma unroll
    for (int q = 0; q < 2; ++q) {
        const int idx = q * 64 + l;          // 0..127 = 4 pairs x 32 rows
        const int pp  = idx >> 5;
        const int rr  = idx & 31;
        vf4 rv = 0.f;
        if (rr < MM) rv = ld4(R + ((size_t)(pair0 + pp) * MM + rr) * 4);
        Rl[w][pp][rr] = rv;
    }

    // ---- per-wave weight setup (amortized over NPAIR pairs) ----
    vf4 w0[4][2];
#pragma unroll
    for (int i = 0; i < 4; ++i) {
        w0[i][0] = ld4(We0 + i * NE + grp * 8);
        w0[i][1] = ld4(We0 + i * NE + grp * 8 + 4);
    }
    const vf4 b0a = ld4(be0 + grp * 8);
    const vf4 b0b = ld4(be0 + grp * 8 + 4);

    bf16x8 B1h[2], B1l[2], B2h[2], B2l[2];
#pragma unroll
    for (int nt = 0; nt < 2; ++nt) {
        const float* wp = We1 + (size_t)(grp * 8) * NE + nt * 16 + row0;
        vf4 x0 = { wp[0],      wp[NE],     wp[2 * NE], wp[3 * NE] };
        vf4 x1 = { wp[4 * NE], wp[5 * NE], wp[6 * NE], wp[7 * NE] };
        split8v(x0, x1, B1h[nt], B1l[nt]);
        const float* wq = We2 + (size_t)(grp * 8) * NE + nt * 16 + row0;
        vf4 y0 = { wq[0],      wq[NE],     wq[2 * NE], wq[3 * NE] };
        vf4 y1 = { wq[4 * NE], wq[5 * NE], wq[6 * NE], wq[7 * NE] };
        split8v(y0, y1, B2h[nt], B2l[nt]);
    }

    const float bias1[2] = { be1[row0], be1[row0 + 16] };
    const float bias2[2] = { be2[row0], be2[row0 + 16] };

    // ---- pair loop ----
    for (int pp = 0; pp < NPAIR; ++pp) {
        const int pair = pair0 + pp;
        const float* __restrict__ sgp = Sg + (size_t)pair * MM * 4;

        // layer 0: 4 -> 32, sigmoid; build A-frags for layer 1
        bf16x8 Ah[2], Al[2];
#pragma unroll
        for (int t = 0; t < 2; ++t) {
            const int p = 16 * t + row0;
            vf4 s = 0.f;
            if (p < MM) s = ld4(sgp + p * 4);
            vf4 acc0 = b0a + s.x * w0[0][0] + s.y * w0[1][0] + s.z * w0[2][0] + s.w * w0[3][0];
            vf4 acc1 = b0b + s.x * w0[0][1] + s.y * w0[1][1] + s.z * w0[2][1] + s.w * w0[3][1];
#pragma unroll
            for (int e = 0; e < 4; ++e) { acc0[e] = fsig(acc0[e]); acc1[e] = fsig(acc1[e]); }
            split8v(acc0, acc1, Ah[t], Al[t]);
        }

        // layer 1 MFMA (bias in accumulator init)
        vf4 H1[2][2];
#pragma unroll
        for (int t = 0; t < 2; ++t)
#pragma unroll
            for (int nt = 0; nt < 2; ++nt) {
                vf4 c = bias1[nt];
                H1[t][nt] = mm3(Ah[t], Al[t], B1h[nt], B1l[nt], c);
            }

        // tanh + transpose via per-wave LDS tile
#pragma unroll
        for (int t = 0; t < 2; ++t)
#pragma unroll
            for (int nt = 0; nt < 2; ++nt)
#pragma unroll
                for (int e = 0; e < 4; ++e)
                    T[w][(grp * 4 + e + 16 * t) * TP + row0 + 16 * nt] = ftanh(H1[t][nt][e]);

        bf16x8 A2h[2], A2l[2];
#pragma unroll
        for (int t = 0; t < 2; ++t) {
            const float* src = &T[w][(16 * t + row0) * TP + grp * 8];
            vf4 x0 = *(const vf4*)(src);
            vf4 x1 = *(const vf4*)(src + 4);
            split8v(x0, x1, A2h[t], A2l[t]);
        }

        // layer 2 MFMA (bias in accumulator init): G = h1' @ We2 + be2
        vf4 G[2][2];
#pragma unroll
        for (int t = 0; t < 2; ++t)
#pragma unroll
            for (int nt = 0; nt < 2; ++nt) {
                vf4 c = bias2[nt];
                G[t][nt] = mm3(A2h[t], A2l[t], B2h[nt], B2l[nt], c);
            }

        // Bm[l][col] = sum_m R[m][l]*G[m][col]; per-lane partial over its 8
        // rows, then xor16/xor32 combine (pad rows have R=0)
        float bm[4][2] = {{0.f, 0.f}, {0.f, 0.f}, {0.f, 0.f}, {0.f, 0.f}};
#pragma unroll
        for (int t = 0; t < 2; ++t)
#pragma unroll
            for (int e = 0; e < 4; ++e) {
                const int rrow = grp * 4 + e + 16 * t;
                const vf4 r4 = Rl[w][pp][rrow];
#pragma unroll
                for (int nt = 0; nt < 2; ++nt) {
                    const float gv = G[t][nt][e];
                    bm[0][nt] += r4.x * gv;
                    bm[1][nt] += r4.y * gv;
                    bm[2][nt] += r4.z * gv;
                    bm[3][nt] += r4.w * gv;
                }
            }
        float bmv[4][2];
#pragma unroll
        for (int li = 0; li < 4; ++li)
#pragma unroll
            for (int nt = 0; nt < 2; ++nt) {
                float v = bm[li][nt];
                v += __shfl_xor(v, 16);
                v += __shfl_xor(v, 32);
                bmv[li][nt] = v;
            }

        // D[k][n] = sum_l Bm[l][k]*Bm[l][n]; lane: k=2grp+kk, n=row0+16nt
        float d[2][2] = {{0.f, 0.f}, {0.f, 0.f}};
#pragma unroll
        for (int kk = 0; kk < 2; ++kk) {
            const int src = grp * 2 + kk;
#pragma unroll
            for (int li = 0; li < 4; ++li) {
                const float a = __shfl(bmv[li][0], src);
#pragma unroll
                for (int nt = 0; nt < 2; ++nt) d[kk][nt] += a * bmv[li][nt];
            }
        }

        float* __restrict__ dp = Dout + (size_t)pair * 256;
#pragma unroll
        for (int kk = 0; kk < 2; ++kk)
#pragma unroll
            for (int nt = 0; nt < 2; ++nt)
                dp[(grp * 2 + kk) * NE + nt * 16 + row0] = d[kk][nt];
    }
}

// ---------------------------------------------------------------------------
// K2 v3: fit MLP, feature-split waves + provably-uniform weight addressing.
// ---------------------------------------------------------------------------
__global__ __launch_bounds__(256) void k_fit2(
    const float* __restrict__ D,
    const float* __restrict__ Wf0, const float* __restrict__ bf0,
    const float* __restrict__ Wf1, const float* __restrict__ bf1,
    const float* __restrict__ Wf2, const float* __restrict__ bf2,
    const float* __restrict__ Wf3, const float* __restrict__ bf3,
    float* __restrict__ Q)
{
    __shared__ float HT0[64 * 64];   // 16 KB, [f][row]
    __shared__ float HT1[64 * 64];   // 16 KB, [f][row]

    const int tid = threadIdx.x;
    const int r   = tid & 63;          // lane: row within block
    const int row = blockIdx.x * 64 + r;
    const int f0  = __builtin_amdgcn_readfirstlane(tid >> 6) * 16;

    // ---- layer 0: 256 -> 64 (this wave: 16 features), k order preserved ----
    float h[16];
#pragma unroll
    for (int j = 0; j < 16; ++j) h[j] = bf0[f0 + j];

    const float4* __restrict__ d4 = (const float4*)(D + (size_t)row * 256);
#pragma unroll 8
    for (int kk = 0; kk < 64; ++kk) {
        const float4 dv = d4[kk];
#pragma unroll
        for (int e = 0; e < 4; ++e) {
            const float dval = (&dv.x)[e];
            const float* __restrict__ wv = Wf0 + (size_t)(kk * 4 + e) * NF + f0;
#pragma unroll
            for (int j = 0; j < 16; ++j) h[j] += dval * wv[j];
        }
    }
#pragma unroll
    for (int j = 0; j < 16; ++j) HT0[(f0 + j) * 64 + r] = ftanh(h[j]);
    __syncthreads();

    // ---- layer 1: 64 -> 64, sigmoid ----
    float h2[16];
#pragma unroll
    for (int j = 0; j < 16; ++j) h2[j] = bf1[f0 + j];
#pragma unroll 8
    for (int k = 0; k < 64; ++k) {
        const float hv = HT0[k * 64 + r];
        const float* __restrict__ wv = Wf1 + (size_t)k * NF + f0;
#pragma unroll
        for (int j = 0; j < 16; ++j) h2[j] += hv * wv[j];
    }
#pragma unroll
    for (int j = 0; j < 16; ++j) HT1[(f0 + j) * 64 + r] = fsig(h2[j]);
    __syncthreads();

    // ---- layer 2: 64 -> 64, tanh (results stay in registers) ----
#pragma unroll
    for (int j = 0; j < 16; ++j) h[j] = bf2[f0 + j];
#pragma unroll 8
    for (int k = 0; k < 64; ++k) {
        const float hv = HT1[k * 64 + r];
        const float* __restrict__ wv = Wf2 + (size_t)k * NF + f0;
#pragma unroll
        for (int j = 0; j < 16; ++j) h[j] += hv * wv[j];
    }

    // ---- layer 3 partial: this wave's 16 features ----
    float qp = 0.f;
#pragma unroll
    for (int j = 0; j < 16; ++j) qp += ftanh(h[j]) * Wf3[f0 + j];

    float* Qp = HT0;   // HT0 dead; reuse
    Qp[(tid >> 6) * 64 + r] = qp;
    __syncthreads();

    if (tid < 64) {
        const float q = bf3[0] + Qp[tid] + Qp[64 + tid] + Qp[128 + tid] + Qp[192 + tid];
        Q[(size_t)blockIdx.x * 64 + tid] = q;
    }
}

// ---------------------------------------------------------------------------
// K3: deterministic mean over N per batch element.
// ---------------------------------------------------------------------------
__global__ __launch_bounds__(256) void k_mean(const float* __restrict__ Q,
                                              float* __restrict__ out)
{
    __shared__ float s[256];
    const int b = blockIdx.x;
    const int t = threadIdx.x;
    float v = Q[b * NN + t] + Q[b * NN + 256 + t];
    s[t] = v;
    __syncthreads();
#pragma unroll
    for (int off = 128; off > 0; off >>= 1) {
        if (t < off) s[t] += s[t + off];
        __syncthreads();
    }
    if (t == 0) out[b] = s[0] * (1.0f / (float)NN);
}

// ---------------------------------------------------------------------------
extern "C" void kernel_launch(void* const* d_in, const int* in_sizes, int n_in,
                              void* d_out, int out_size, void* d_ws, size_t ws_size,
                              hipStream_t stream)
{
    const float* Sg  = (const float*)d_in[0];
    const float* R   = (const float*)d_in[1];
    const float* We0 = (const float*)d_in[2];
    const float* be0 = (const float*)d_in[3];
    const float* We1 = (const float*)d_in[4];
    const float* be1 = (const float*)d_in[5];
    const float* We2 = (const float*)d_in[6];
    const float* be2 = (const float*)d_in[7];
    const float* Wf0 = (const float*)d_in[8];
    const float* bf0 = (const float*)d_in[9];
    const float* Wf1 = (const float*)d_in[10];
    const float* bf1 = (const float*)d_in[11];
    const float* Wf2 = (const float*)d_in[12];
    const float* bf2 = (const float*)d_in[13];
    const float* Wf3 = (const float*)d_in[14];
    const float* bf3 = (const float*)d_in[15];

    float* D = (float*)d_ws;                                  // 33.55 MB
    float* Q = (float*)((char*)d_ws + (size_t)BN_TOTAL * 256 * sizeof(float)); // 128 KB

    k_emb_mfma<<<BN_TOTAL / (4 * NPAIR), 256, 0, stream>>>(Sg, R, We0, be0, We1, be1, We2, be2, D);
    k_fit2<<<BN_TOTAL / 64, 256, 0, stream>>>(D, Wf0, bf0, Wf1, bf1, Wf2, bf2, Wf3, bf3, Q);
    k_mean<<<BB, 256, 0, stream>>>(Q, (float*)d_out);
}